// Round 7
// baseline (175.350 us; speedup 1.0000x reference)
//
#include <hip/hip_runtime.h>

#define NPAIR 8192   // B*NCG

// Single fused kernel. Table phase (batch-independent, ~430K lane-ops) is
// computed redundantly per block into LDS: costs ~3 us of concurrent work vs
// a ~40 us serialized precompute dispatch + inter-kernel gap. All math is the
// R6-proven fp32 path. launch_bounds(512,4): 128-VGPR cap (R6's (512,8)
// forced 32 VGPRs -> 30 MB scratch spill traffic, the 44->53us regression).
__global__ __launch_bounds__(512, 4) void fused_kernel(
    const int*   __restrict__ archs,
    const float* __restrict__ init_emb, const float* __restrict__ other_emb,
    const float* __restrict__ op_embs,  const float* __restrict__ Wx,
    const float* __restrict__ bx,       const float* __restrict__ W1,
    const float* __restrict__ Wa1,      const float* __restrict__ ba1,
    const float* __restrict__ W2,       const float* __restrict__ Wa2,
    const float* __restrict__ ba2,      float* __restrict__ out)
{
  __shared__ float y0[576];        // node @ Wx + bx       [2][6][48]
  __shared__ float s1sh[1536];     // support1             [2][6][128]
  __shared__ float at1sh[896];     // sigmoid attn L1      [7][128], row0 = 0
  __shared__ float at2sh[896];     // sigmoid attn L2      [7][128], row0 = 0
  __shared__ float s2ish[512];     // support2, init nodes [2][2][128]
  __shared__ float y1sh[16 * 512]; // relu(layer1 out)     [16 pairs][4][128]

  const int t = threadIdx.x;

  // ================= Phase T: tables (redundant per block) =================
  // stage 1: y0[c][i][h] = node @ Wx + bx
  for (int idx = t; idx < 576; idx += 512) {
    int c = idx / 288, i = (idx / 48) % 6, h = idx % 48;
    const float* nptr = (i < 2) ? (init_emb + (c * 2 + i) * 48)
                                : (other_emb + c * 48);
    float acc = bx[h];
    #pragma unroll
    for (int d = 0; d < 48; ++d) acc += nptr[d] * Wx[d * 48 + h];
    y0[idx] = acc;
  }
  // stage 3 (independent of stage 1): attn tables, NONE mask baked into row 0
  for (int idx = t; idx < 896; idx += 512) {
    int op = idx >> 7, o = idx & 127;
    float a1 = ba1[o], a2 = ba2[o];
    #pragma unroll
    for (int d = 0; d < 48; ++d) {
      float e = op_embs[op * 48 + d];
      a1 += e * Wa1[d * 128 + o];
      a2 += e * Wa2[d * 128 + o];
    }
    bool z = (op == 0);
    at1sh[idx] = z ? 0.f : 1.f / (1.f + __expf(-a1));
    at2sh[idx] = z ? 0.f : 1.f / (1.f + __expf(-a2));
  }
  __syncthreads();

  // stage 2: support1[ci][o] = y0 @ W1
  for (int idx = t; idx < 1536; idx += 512) {
    int ci = idx >> 7, o = idx & 127;
    const float* yp = y0 + ci * 48;
    float acc = 0.f;
    #pragma unroll
    for (int h = 0; h < 48; ++h) acc += yp[h] * W1[h * 128 + o];
    s1sh[idx] = acc;
  }
  __syncthreads();

  // stage 4: support2 for init nodes (no in-edges -> y1 = relu(support1)).
  // 512 outputs, exactly one per thread. Read by epilogue (after next sync).
  {
    int c = t >> 8, i = (t >> 7) & 1, o = t & 127;
    const float* sp = s1sh + (c * 6 + i) * 128;
    float acc = 0.f;
    #pragma unroll
    for (int h = 0; h < 128; ++h) acc += fmaxf(sp[h], 0.f) * W2[h * 128 + o];
    s2ish[(c * 2 + i) * 128 + o] = acc;
  }

  // ================= Phase G: per-pair layer1 + gemm + layer2 ==============
  // wave w handles pairs p0 = blk*16 + 2w (c=0) and p1 = p0+1 (c=1)
  const int w  = __builtin_amdgcn_readfirstlane(t >> 6);
  const int o2 = t & 63;                  // channel pair 2*o2, 2*o2+1
  const int p0 = blockIdx.x * 16 + w * 2;

  const int* ap0 = archs + p0 * 16;       // wave-uniform -> scalar loads
  const int* ap1 = ap0 + 16;
  int f0[8], g0[8], f1[8], g1[8];
  #pragma unroll
  for (int e = 0; e < 8; ++e) {
    f0[e] = ap0[e]; g0[e] = ap0[8 + e];
    f1[e] = ap1[e]; g1[e] = ap1[8 + e];
  }

  const float2* s1f = (const float2*)s1sh;   // [12][64]
  const float2* a1f = (const float2*)at1sh;  // [7][64]

  // layer 1 for both pairs (s1sh/at1sh ready since last sync)
  #pragma unroll
  for (int pi = 0; pi < 2; ++pi) {
    const int* f  = pi ? f1 : f0;
    const int* g  = pi ? g1 : g0;
    const int  cb = pi * 384;              // c*6*64 in float2
    float* yd = y1sh + (w * 2 + pi) * 512;
    #pragma unroll
    for (int i = 0; i < 4; ++i) {
      float2 v  = s1f[cb + (2 + i) * 64 + o2];
      int e0 = 2 * i, e1 = 2 * i + 1;
      float2 A0 = a1f[g[e0] * 64 + o2];
      float2 B0 = s1f[cb + f[e0] * 64 + o2];
      float2 A1 = a1f[g[e1] * 64 + o2];
      float2 B1 = s1f[cb + f[e1] * 64 + o2];
      v.x += A0.x * B0.x + A1.x * B1.x;
      v.y += A0.y * B0.y + A1.y * B1.y;
      ((float2*)(yd + i * 128))[o2] = make_float2(fmaxf(v.x, 0.f), fmaxf(v.y, 0.f));
    }
  }
  __syncthreads();   // y1sh + s2ish ready

  // gemm: 2 pairs x 4 nodes x 2 channels per lane; one W2 float2 feeds 16 FMA
  const float* ya = y1sh + (w * 2) * 512;
  const float* yb = ya + 512;
  const float2* W2f = (const float2*)W2;

  float ax0 = 0, ax1 = 0, ax2 = 0, ax3 = 0, ay0 = 0, ay1 = 0, ay2 = 0, ay3 = 0;
  float bx0 = 0, bx1 = 0, bx2 = 0, bx3 = 0, by0 = 0, by1 = 0, by2 = 0, by3 = 0;

  #define COMP4(v, j) ((j) == 0 ? (v).x : (j) == 1 ? (v).y : (j) == 2 ? (v).z : (v).w)
  for (int h = 0; h < 128; h += 4) {
    float4 qa0 = *(const float4*)(ya + 0 * 128 + h);  // wave-broadcast LDS
    float4 qa1 = *(const float4*)(ya + 1 * 128 + h);
    float4 qa2 = *(const float4*)(ya + 2 * 128 + h);
    float4 qa3 = *(const float4*)(ya + 3 * 128 + h);
    float4 qb0 = *(const float4*)(yb + 0 * 128 + h);
    float4 qb1 = *(const float4*)(yb + 1 * 128 + h);
    float4 qb2 = *(const float4*)(yb + 2 * 128 + h);
    float4 qb3 = *(const float4*)(yb + 3 * 128 + h);
    #pragma unroll
    for (int j = 0; j < 4; ++j) {
      float2 wf = W2f[(h + j) * 64 + o2];
      float w0 = wf.x, w1 = wf.y, y;
      y = COMP4(qa0, j); ax0 += y * w0; ay0 += y * w1;
      y = COMP4(qa1, j); ax1 += y * w0; ay1 += y * w1;
      y = COMP4(qa2, j); ax2 += y * w0; ay2 += y * w1;
      y = COMP4(qa3, j); ax3 += y * w0; ay3 += y * w1;
      y = COMP4(qb0, j); bx0 += y * w0; by0 += y * w1;
      y = COMP4(qb1, j); bx1 += y * w0; by1 += y * w1;
      y = COMP4(qb2, j); bx2 += y * w0; by2 += y * w1;
      y = COMP4(qb3, j); bx3 += y * w0; by3 += y * w1;
    }
  }

  // layer-2 edge aggregation + mean over nodes 2..5, both pairs
  const float2* a2f = (const float2*)at2sh;   // [7][64]
  const float2* s2f = (const float2*)s2ish;   // [4][64] = [c*2+i][64]

  {  // pair 0 (c=0)
    float2 S0 = s2f[o2], S1 = s2f[64 + o2];
    float r0 = ax0 + ax1 + ax2 + ax3;
    float r1 = ay0 + ay1 + ay2 + ay3;
    #pragma unroll
    for (int e = 0; e < 8; ++e) {
      float2 a = a2f[g0[e] * 64 + o2];
      int fe = f0[e];
      float sx, sy;
      if (fe == 0)      { sx = S0.x; sy = S0.y; }
      else if (fe == 1) { sx = S1.x; sy = S1.y; }
      else if (fe == 2) { sx = ax0; sy = ay0; }
      else if (fe == 3) { sx = ax1; sy = ay1; }
      else if (fe == 4) { sx = ax2; sy = ay2; }
      else              { sx = ax3; sy = ay3; }
      r0 += a.x * sx;
      r1 += a.y * sy;
    }
    ((float2*)out)[p0 * 64 + o2] = make_float2(r0 * 0.25f, r1 * 0.25f);
  }
  {  // pair 1 (c=1)
    float2 S0 = s2f[128 + o2], S1 = s2f[192 + o2];
    float r0 = bx0 + bx1 + bx2 + bx3;
    float r1 = by0 + by1 + by2 + by3;
    #pragma unroll
    for (int e = 0; e < 8; ++e) {
      float2 a = a2f[g1[e] * 64 + o2];
      int fe = f1[e];
      float sx, sy;
      if (fe == 0)      { sx = S0.x; sy = S0.y; }
      else if (fe == 1) { sx = S1.x; sy = S1.y; }
      else if (fe == 2) { sx = bx0; sy = by0; }
      else if (fe == 3) { sx = bx1; sy = by1; }
      else if (fe == 4) { sx = bx2; sy = by2; }
      else              { sx = bx3; sy = by3; }
      r0 += a.x * sx;
      r1 += a.y * sy;
    }
    ((float2*)out)[(p0 + 1) * 64 + o2] = make_float2(r0 * 0.25f, r1 * 0.25f);
  }
}

extern "C" void kernel_launch(void* const* d_in, const int* in_sizes, int n_in,
                              void* d_out, int out_size, void* d_ws, size_t ws_size,
                              hipStream_t stream) {
  fused_kernel<<<NPAIR / 16, 512, 0, stream>>>(
      (const int*)d_in[0],
      (const float*)d_in[1], (const float*)d_in[2], (const float*)d_in[3],
      (const float*)d_in[4], (const float*)d_in[5], (const float*)d_in[6],
      (const float*)d_in[7], (const float*)d_in[8], (const float*)d_in[9],
      (const float*)d_in[10], (const float*)d_in[11], (float*)d_out);
}